// Round 1
// baseline (890.316 us; speedup 1.0000x reference)
//
#include <hip/hip_runtime.h>
#include <hip/hip_bf16.h>
#include <math.h>

#define Bc 32
#define Cc 64
#define Sc 128
#define Zc 64
#define Dc 256
#define VIc 30000
#define VOc 5000
#define EST 68   // e LDS row stride (pad; 68*4 bytes is 16B-aligned)

// ---------------------------------------------------------------------------
// K1/K2: row transform GEMM.  out = (gathered Emb rows) @ [FW | GW1 | GW2]
//   seg 0: relu(row@FW + Fb) -> outM
//   seg 1: row@GW[0:256]     -> outT
//   seg 2: row@GW[256:512]   -> outU
// grid = (ceil(nrows/64), 6), block = 256, thread tile 4x8, BM=64 BN=128 KC=32
// ---------------------------------------------------------------------------
__global__ __launch_bounds__(256) void transform_kernel(
    const float* __restrict__ Emb, const int* __restrict__ idx, int nrows,
    const float* __restrict__ FW, const float* __restrict__ Fb,
    const float* __restrict__ GW,
    float* __restrict__ outM, float* __restrict__ outT, float* __restrict__ outU)
{
  const int rb = blockIdx.x, cb = blockIdx.y;
  const int row0 = rb * 64;
  const int seg = cb >> 1;               // 0:FW  1:GW1  2:GW2
  const int colbase = (cb & 1) * 128;    // column offset within the 256-col segment
  const float* W = (seg == 0) ? FW : GW;
  const int rowoff = (seg == 2) ? Dc : 0;

  __shared__ float As[32][68];    // [k][m]  (transposed A chunk)
  __shared__ float Ws[32][132];   // [k][n]

  const int t = threadIdx.x;
  const int mt = t >> 4, nt = t & 15;
  const int m0 = mt * 4, n0 = nt * 8;
  float acc[4][8];
#pragma unroll
  for (int i = 0; i < 4; ++i)
#pragma unroll
    for (int j = 0; j < 8; ++j) acc[i][j] = 0.f;

  for (int k0 = 0; k0 < Dc; k0 += 32) {
#pragma unroll
    for (int i = 0; i < 2; ++i) {               // stage A: 64 rows x 32 k
      int f = t + i * 256;
      int m = f >> 3, kq = f & 7;
      int r = row0 + m; if (r > nrows - 1) r = nrows - 1;
      int src = idx ? idx[r] : r;
      float4 v = *(const float4*)&Emb[(size_t)src * Dc + k0 + kq * 4];
      As[kq * 4 + 0][m] = v.x; As[kq * 4 + 1][m] = v.y;
      As[kq * 4 + 2][m] = v.z; As[kq * 4 + 3][m] = v.w;
    }
#pragma unroll
    for (int i = 0; i < 4; ++i) {               // stage W: 32 k x 128 n
      int f = t + i * 256;
      int k = f >> 5, nq = f & 31;
      float4 v = *(const float4*)&W[(size_t)(rowoff + k0 + k) * Dc + colbase + nq * 4];
      *(float4*)&Ws[k][nq * 4] = v;
    }
    __syncthreads();
#pragma unroll
    for (int k = 0; k < 32; ++k) {
      float a[4], w[8];
      *(float4*)&a[0] = *(const float4*)&As[k][m0];
      *(float4*)&w[0] = *(const float4*)&Ws[k][n0];
      *(float4*)&w[4] = *(const float4*)&Ws[k][n0 + 4];
#pragma unroll
      for (int i = 0; i < 4; ++i)
#pragma unroll
        for (int j = 0; j < 8; ++j) acc[i][j] = fmaf(a[i], w[j], acc[i][j]);
    }
    __syncthreads();
  }

  float* outp = (seg == 0) ? outM : ((seg == 1) ? outT : outU);
  float bias[8];
  if (seg == 0) {
    *(float4*)&bias[0] = *(const float4*)&Fb[colbase + n0];
    *(float4*)&bias[4] = *(const float4*)&Fb[colbase + n0 + 4];
  }
#pragma unroll
  for (int i = 0; i < 4; ++i) {
    int r = row0 + m0 + i;
    if (r >= nrows) continue;
    float o[8];
#pragma unroll
    for (int j = 0; j < 8; ++j) {
      float v = acc[i][j];
      if (seg == 0) v = fmaxf(v + bias[j], 0.f);
      o[j] = v;
    }
    *(float4*)&outp[(size_t)r * Dc + colbase + n0]     = *(float4*)&o[0];
    *(float4*)&outp[(size_t)r * Dc + colbase + n0 + 4] = *(float4*)&o[4];
  }
}

// ---------------------------------------------------------------------------
// K5: per-(b,c) block. e[s][z] = Am[b,s,:]·FB[cand[z],:] ; alpha = softmax over s;
// P2[z,g] = sum_s alpha[s,z]*Ua[b,s,g]; V2[g] = sum_z relu(Tb[cand[z],g]+P2+Gb)
// ---------------------------------------------------------------------------
__global__ __launch_bounds__(256) void v2_kernel(
    const int* __restrict__ cand, const float* __restrict__ Am,
    const float* __restrict__ FBv, const float* __restrict__ Ua,
    const float* __restrict__ Tb, const float* __restrict__ Gb,
    float* __restrict__ V2)
{
  const int bc = blockIdx.x;
  const int b = bc >> 6;
  const int t = threadIdx.x;

  __shared__ float e[Sc][EST];
  __shared__ float As[32][132];
  __shared__ float Bs[32][EST];
  __shared__ int   cidx[Zc];
  __shared__ float stat[4][Zc];
  __shared__ float cmax[Zc];
  __shared__ float crcp[Zc];
  __shared__ float red[8][256];

  if (t < Zc) cidx[t] = cand[(size_t)bc * Zc + t];
  __syncthreads();

  // ---- phase 1: e = Am[b] (SxD) @ FBc^T (DxZ), thread tile 4s x 8z ----
  const int st = t & 31, zt = t >> 5;
  const int s0 = st * 4, z0 = zt * 8;
  float acc[4][8];
#pragma unroll
  for (int i = 0; i < 4; ++i)
#pragma unroll
    for (int j = 0; j < 8; ++j) acc[i][j] = 0.f;

  for (int k0 = 0; k0 < Dc; k0 += 32) {
#pragma unroll
    for (int i = 0; i < 4; ++i) {               // stage Am chunk transposed
      int f = t + i * 256;
      int s = f >> 3, kq = f & 7;
      float4 v = *(const float4*)&Am[((size_t)(b * Sc + s)) * Dc + k0 + kq * 4];
      As[kq * 4 + 0][s] = v.x; As[kq * 4 + 1][s] = v.y;
      As[kq * 4 + 2][s] = v.z; As[kq * 4 + 3][s] = v.w;
    }
#pragma unroll
    for (int i = 0; i < 2; ++i) {               // stage FBc chunk transposed
      int f = t + i * 256;
      int z = f >> 3, kq = f & 7;
      float4 v = *(const float4*)&FBv[((size_t)cidx[z]) * Dc + k0 + kq * 4];
      Bs[kq * 4 + 0][z] = v.x; Bs[kq * 4 + 1][z] = v.y;
      Bs[kq * 4 + 2][z] = v.z; Bs[kq * 4 + 3][z] = v.w;
    }
    __syncthreads();
#pragma unroll
    for (int k = 0; k < 32; ++k) {
      float a[4], w[8];
      *(float4*)&a[0] = *(const float4*)&As[k][s0];
      *(float4*)&w[0] = *(const float4*)&Bs[k][z0];
      *(float4*)&w[4] = *(const float4*)&Bs[k][z0 + 4];
#pragma unroll
      for (int i = 0; i < 4; ++i)
#pragma unroll
        for (int j = 0; j < 8; ++j) acc[i][j] = fmaf(a[i], w[j], acc[i][j]);
    }
    __syncthreads();
  }
#pragma unroll
  for (int i = 0; i < 4; ++i) {
    *(float4*)&e[s0 + i][z0]     = *(float4*)&acc[i][0];
    *(float4*)&e[s0 + i][z0 + 4] = *(float4*)&acc[i][4];
  }
  __syncthreads();

  // ---- phase 2: column softmax stats (over s), transform e -> alpha in place
  {
    int z = t & 63, q = t >> 6;
    float m = -1e30f;
    for (int s = q * 32; s < q * 32 + 32; ++s) m = fmaxf(m, e[s][z]);
    stat[q][z] = m;
  }
  __syncthreads();
  if (t < Zc) cmax[t] = fmaxf(fmaxf(stat[0][t], stat[1][t]), fmaxf(stat[2][t], stat[3][t]));
  __syncthreads();
  {
    int z = t & 63, q = t >> 6;
    float mm = cmax[z], sum = 0.f;
    for (int s = q * 32; s < q * 32 + 32; ++s) sum += __expf(e[s][z] - mm);
    stat[q][z] = sum;
  }
  __syncthreads();
  if (t < Zc) crcp[t] = 1.f / (stat[0][t] + stat[1][t] + stat[2][t] + stat[3][t]);
  __syncthreads();
  {
    float cm[8], cr[8];
    *(float4*)&cm[0] = *(float4*)&cmax[z0]; *(float4*)&cm[4] = *(float4*)&cmax[z0 + 4];
    *(float4*)&cr[0] = *(float4*)&crcp[z0]; *(float4*)&cr[4] = *(float4*)&crcp[z0 + 4];
#pragma unroll
    for (int i = 0; i < 4; ++i) {
      float o[8];
#pragma unroll
      for (int j = 0; j < 8; ++j) o[j] = __expf(acc[i][j] - cm[j]) * cr[j];
      *(float4*)&e[s0 + i][z0]     = *(float4*)&o[0];
      *(float4*)&e[s0 + i][z0 + 4] = *(float4*)&o[4];
    }
  }
  __syncthreads();

  // ---- phase 3: P2 (ZxG) = alpha^T @ Ua[b], thread tile 8z x 8g ----
  const int gt = t & 31, zt2 = t >> 5;
  const int g0 = gt * 8, zz0 = zt2 * 8;
  float acc2[8][8];
#pragma unroll
  for (int i = 0; i < 8; ++i)
#pragma unroll
    for (int j = 0; j < 8; ++j) acc2[i][j] = 0.f;

  for (int s = 0; s < Sc; ++s) {
    float al[8], u[8];
    *(float4*)&al[0] = *(const float4*)&e[s][zz0];
    *(float4*)&al[4] = *(const float4*)&e[s][zz0 + 4];
    const float* up = &Ua[((size_t)(b * Sc + s)) * Dc + g0];
    *(float4*)&u[0] = *(const float4*)&up[0];
    *(float4*)&u[4] = *(const float4*)&up[4];
#pragma unroll
    for (int i = 0; i < 8; ++i)
#pragma unroll
      for (int j = 0; j < 8; ++j) acc2[i][j] = fmaf(al[i], u[j], acc2[i][j]);
  }

  // ---- epilogue: relu + sum over z ----
  float gbv[8];
  *(float4*)&gbv[0] = *(const float4*)&Gb[g0];
  *(float4*)&gbv[4] = *(const float4*)&Gb[g0 + 4];
  float sv[8];
#pragma unroll
  for (int j = 0; j < 8; ++j) sv[j] = 0.f;
#pragma unroll
  for (int zi = 0; zi < 8; ++zi) {
    const float* tp = &Tb[((size_t)cidx[zz0 + zi]) * Dc + g0];
    float tb[8];
    *(float4*)&tb[0] = *(const float4*)&tp[0];
    *(float4*)&tb[4] = *(const float4*)&tp[4];
#pragma unroll
    for (int j = 0; j < 8; ++j)
      sv[j] += fmaxf(acc2[zi][j] + tb[j] + gbv[j], 0.f);
  }
  *(float4*)&red[zt2][g0]     = *(float4*)&sv[0];
  *(float4*)&red[zt2][g0 + 4] = *(float4*)&sv[4];
  __syncthreads();
  float tot = 0.f;
#pragma unroll
  for (int q = 0; q < 8; ++q) tot += red[q][t];
  V2[(size_t)bc * Dc + t] = tot;
}

// ---------------------------------------------------------------------------
// K6: per-(b,c) block. Same e; beta = softmax over z;
// P1[s,g] = sum_z beta[s,z]*Ub[cand[z],g]; V1[g] = sum_s relu(Ta[b,s,g]+P1+Gb)
// ---------------------------------------------------------------------------
__global__ __launch_bounds__(256) void v1_kernel(
    const int* __restrict__ cand, const float* __restrict__ Am,
    const float* __restrict__ FBv, const float* __restrict__ Ub,
    const float* __restrict__ Ta, const float* __restrict__ Gb,
    float* __restrict__ V1)
{
  const int bc = blockIdx.x;
  const int b = bc >> 6;
  const int t = threadIdx.x;

  __shared__ float e[Sc][EST];
  __shared__ float As[32][132];
  __shared__ float Bs[32][EST];
  __shared__ int   cidx[Zc];
  __shared__ float stat2[2][Sc];
  __shared__ float rmax[Sc];
  __shared__ float rrcp[Sc];
  __shared__ float red[8][256];

  if (t < Zc) cidx[t] = cand[(size_t)bc * Zc + t];
  __syncthreads();

  // ---- phase 1: identical e computation ----
  const int st = t & 31, zt = t >> 5;
  const int s0 = st * 4, z0 = zt * 8;
  float acc[4][8];
#pragma unroll
  for (int i = 0; i < 4; ++i)
#pragma unroll
    for (int j = 0; j < 8; ++j) acc[i][j] = 0.f;

  for (int k0 = 0; k0 < Dc; k0 += 32) {
#pragma unroll
    for (int i = 0; i < 4; ++i) {
      int f = t + i * 256;
      int s = f >> 3, kq = f & 7;
      float4 v = *(const float4*)&Am[((size_t)(b * Sc + s)) * Dc + k0 + kq * 4];
      As[kq * 4 + 0][s] = v.x; As[kq * 4 + 1][s] = v.y;
      As[kq * 4 + 2][s] = v.z; As[kq * 4 + 3][s] = v.w;
    }
#pragma unroll
    for (int i = 0; i < 2; ++i) {
      int f = t + i * 256;
      int z = f >> 3, kq = f & 7;
      float4 v = *(const float4*)&FBv[((size_t)cidx[z]) * Dc + k0 + kq * 4];
      Bs[kq * 4 + 0][z] = v.x; Bs[kq * 4 + 1][z] = v.y;
      Bs[kq * 4 + 2][z] = v.z; Bs[kq * 4 + 3][z] = v.w;
    }
    __syncthreads();
#pragma unroll
    for (int k = 0; k < 32; ++k) {
      float a[4], w[8];
      *(float4*)&a[0] = *(const float4*)&As[k][s0];
      *(float4*)&w[0] = *(const float4*)&Bs[k][z0];
      *(float4*)&w[4] = *(const float4*)&Bs[k][z0 + 4];
#pragma unroll
      for (int i = 0; i < 4; ++i)
#pragma unroll
        for (int j = 0; j < 8; ++j) acc[i][j] = fmaf(a[i], w[j], acc[i][j]);
    }
    __syncthreads();
  }
#pragma unroll
  for (int i = 0; i < 4; ++i) {
    *(float4*)&e[s0 + i][z0]     = *(float4*)&acc[i][0];
    *(float4*)&e[s0 + i][z0 + 4] = *(float4*)&acc[i][4];
  }
  __syncthreads();

  // ---- phase 2: row softmax stats (over z), transform e -> beta in place ----
  {
    int s = t & 127, q = t >> 7;
    float m = -1e30f;
    for (int z = q * 32; z < q * 32 + 32; ++z) m = fmaxf(m, e[s][z]);
    stat2[q][s] = m;
  }
  __syncthreads();
  if (t < Sc) rmax[t] = fmaxf(stat2[0][t], stat2[1][t]);
  __syncthreads();
  {
    int s = t & 127, q = t >> 7;
    float mm = rmax[s], sum = 0.f;
    for (int z = q * 32; z < q * 32 + 32; ++z) sum += __expf(e[s][z] - mm);
    stat2[q][s] = sum;
  }
  __syncthreads();
  if (t < Sc) rrcp[t] = 1.f / (stat2[0][t] + stat2[1][t]);
  __syncthreads();
  {
#pragma unroll
    for (int i = 0; i < 4; ++i) {
      float mm = rmax[s0 + i], rc = rrcp[s0 + i];
      float o[8];
#pragma unroll
      for (int j = 0; j < 8; ++j) o[j] = __expf(acc[i][j] - mm) * rc;
      *(float4*)&e[s0 + i][z0]     = *(float4*)&o[0];
      *(float4*)&e[s0 + i][z0 + 4] = *(float4*)&o[4];
    }
  }
  __syncthreads();

  // ---- phase 3: two passes over s-halves, thread tile 8s x 8g ----
  const int gt = t & 31, st2 = t >> 5;
  const int g0 = gt * 8;
  float gbv[8];
  *(float4*)&gbv[0] = *(const float4*)&Gb[g0];
  *(float4*)&gbv[4] = *(const float4*)&Gb[g0 + 4];
  float v1tot = 0.f;

  for (int p = 0; p < 2; ++p) {
    const int sbase = p * 64 + st2 * 8;
    float acc1[8][8];
#pragma unroll
    for (int i = 0; i < 8; ++i)
#pragma unroll
      for (int j = 0; j < 8; ++j) acc1[i][j] = 0.f;

    for (int z = 0; z < Zc; ++z) {
      float bt[8];
#pragma unroll
      for (int i = 0; i < 8; ++i) bt[i] = e[sbase + i][z];
      const float* up = &Ub[((size_t)cidx[z]) * Dc + g0];
      float u[8];
      *(float4*)&u[0] = *(const float4*)&up[0];
      *(float4*)&u[4] = *(const float4*)&up[4];
#pragma unroll
      for (int i = 0; i < 8; ++i)
#pragma unroll
        for (int j = 0; j < 8; ++j) acc1[i][j] = fmaf(bt[i], u[j], acc1[i][j]);
    }

    float sv[8];
#pragma unroll
    for (int j = 0; j < 8; ++j) sv[j] = 0.f;
#pragma unroll
    for (int i = 0; i < 8; ++i) {
      const float* tp = &Ta[((size_t)(b * Sc + sbase + i)) * Dc + g0];
      float ta[8];
      *(float4*)&ta[0] = *(const float4*)&tp[0];
      *(float4*)&ta[4] = *(const float4*)&tp[4];
#pragma unroll
      for (int j = 0; j < 8; ++j)
        sv[j] += fmaxf(acc1[i][j] + ta[j] + gbv[j], 0.f);
    }
    __syncthreads();   // protect red reuse across passes
    *(float4*)&red[st2][g0]     = *(float4*)&sv[0];
    *(float4*)&red[st2][g0 + 4] = *(float4*)&sv[4];
    __syncthreads();
    float s8 = 0.f;
#pragma unroll
    for (int q = 0; q < 8; ++q) s8 += red[q][t];
    v1tot += s8;
  }
  V1[(size_t)bc * Dc + t] = v1tot;
}

// ---------------------------------------------------------------------------
// K7: y[bc] = V1[bc]·HW[0:256] + V2[bc]·HW[256:512] + Hb
// ---------------------------------------------------------------------------
__global__ __launch_bounds__(256) void final_kernel(
    const float* __restrict__ V1, const float* __restrict__ V2,
    const float* __restrict__ HW, const float* __restrict__ Hb,
    float* __restrict__ y)
{
  const int t = threadIdx.x;
  const int w = t >> 6, l = t & 63;
  const int bc = blockIdx.x * 4 + w;
  float4 v1 = *(const float4*)&V1[(size_t)bc * Dc + l * 4];
  float4 h1 = *(const float4*)&HW[l * 4];
  float4 v2 = *(const float4*)&V2[(size_t)bc * Dc + l * 4];
  float4 h2 = *(const float4*)&HW[Dc + l * 4];
  float sum = v1.x * h1.x + v1.y * h1.y + v1.z * h1.z + v1.w * h1.w
            + v2.x * h2.x + v2.y * h2.y + v2.z * h2.z + v2.w * h2.w;
#pragma unroll
  for (int off = 32; off > 0; off >>= 1) sum += __shfl_down(sum, off);
  if (l == 0) y[bc] = sum + Hb[0];
}

extern "C" void kernel_launch(void* const* d_in, const int* in_sizes, int n_in,
                              void* d_out, int out_size, void* d_ws, size_t ws_size,
                              hipStream_t stream) {
  (void)in_sizes; (void)n_in; (void)out_size; (void)ws_size;
  const int*   inp  = (const int*)d_in[0];
  const int*   cand = (const int*)d_in[1];
  const float* EmbA = (const float*)d_in[4];
  const float* EmbB = (const float*)d_in[5];
  const float* FW   = (const float*)d_in[6];
  const float* Fb   = (const float*)d_in[7];
  const float* GW   = (const float*)d_in[8];
  const float* Gb   = (const float*)d_in[9];
  const float* HW   = (const float*)d_in[10];
  const float* Hb   = (const float*)d_in[11];
  float* y = (float*)d_out;

  float* ws = (float*)d_ws;
  const size_t nA = (size_t)Bc * Sc * Dc;   // 1,048,576
  const size_t nB = (size_t)VOc * Dc;       // 1,280,000
  const size_t nV = (size_t)Bc * Cc * Dc;   //   524,288
  float* Am  = ws;
  float* Ta  = Am + nA;
  float* Ua  = Ta + nA;
  float* FBv = Ua + nA;
  float* Tb  = FBv + nB;
  float* Ub  = Tb + nB;
  float* V1  = Ub + nB;
  float* V2  = V1 + nV;
  // total ws use: (3*nA + 3*nB + 2*nV)*4 bytes ≈ 32.1 MB

  transform_kernel<<<dim3((Bc * Sc) / 64, 6), 256, 0, stream>>>(
      EmbA, inp, Bc * Sc, FW, Fb, GW, Am, Ta, Ua);
  transform_kernel<<<dim3((VOc + 63) / 64, 6), 256, 0, stream>>>(
      EmbB, nullptr, VOc, FW, Fb, GW, FBv, Tb, Ub);
  v2_kernel<<<Bc * Cc, 256, 0, stream>>>(cand, Am, FBv, Ua, Tb, Gb, V2);
  v1_kernel<<<Bc * Cc, 256, 0, stream>>>(cand, Am, FBv, Ub, Ta, Gb, V1);
  final_kernel<<<(Bc * Cc) / 4, 256, 0, stream>>>(V1, V2, HW, Hb, y);
}

// Round 2
// 497.792 us; speedup vs baseline: 1.7885x; 1.7885x over previous
//
#include <hip/hip_runtime.h>
#include <hip/hip_bf16.h>
#include <math.h>

#define Bc 32
#define Cc 64
#define Sc 128
#define Zc 64
#define Dc 256
#define VOc 5000

// ---------------------------------------------------------------------------
// K1/K2: row transform GEMM.  out = (gathered Emb rows) @ [FW | GW1 | GW2]
//   seg 0: relu(row@FW + Fb) -> outM
//   seg 1: row@GW[0:256]     -> outT
//   seg 2: row@GW[256:512]   -> outU
// ---------------------------------------------------------------------------
__global__ __launch_bounds__(256) void transform_kernel(
    const float* __restrict__ Emb, const int* __restrict__ idx, int nrows,
    const float* __restrict__ FW, const float* __restrict__ Fb,
    const float* __restrict__ GW,
    float* __restrict__ outM, float* __restrict__ outT, float* __restrict__ outU)
{
  const int rb = blockIdx.x, cb = blockIdx.y;
  const int row0 = rb * 64;
  const int seg = cb >> 1;
  const int colbase = (cb & 1) * 128;
  const float* W = (seg == 0) ? FW : GW;
  const int rowoff = (seg == 2) ? Dc : 0;

  __shared__ float As[32][68];
  __shared__ float Ws[32][132];

  const int t = threadIdx.x;
  const int mt = t >> 4, nt = t & 15;
  const int m0 = mt * 4, n0 = nt * 8;
  float acc[4][8];
#pragma unroll
  for (int i = 0; i < 4; ++i)
#pragma unroll
    for (int j = 0; j < 8; ++j) acc[i][j] = 0.f;

  for (int k0 = 0; k0 < Dc; k0 += 32) {
#pragma unroll
    for (int i = 0; i < 2; ++i) {
      int f = t + i * 256;
      int m = f >> 3, kq = f & 7;
      int r = row0 + m; if (r > nrows - 1) r = nrows - 1;
      int src = idx ? idx[r] : r;
      float4 v = *(const float4*)&Emb[(size_t)src * Dc + k0 + kq * 4];
      As[kq * 4 + 0][m] = v.x; As[kq * 4 + 1][m] = v.y;
      As[kq * 4 + 2][m] = v.z; As[kq * 4 + 3][m] = v.w;
    }
#pragma unroll
    for (int i = 0; i < 4; ++i) {
      int f = t + i * 256;
      int k = f >> 5, nq = f & 31;
      float4 v = *(const float4*)&W[(size_t)(rowoff + k0 + k) * Dc + colbase + nq * 4];
      *(float4*)&Ws[k][nq * 4] = v;
    }
    __syncthreads();
#pragma unroll
    for (int k = 0; k < 32; ++k) {
      float a[4], w[8];
      *(float4*)&a[0] = *(const float4*)&As[k][m0];
      *(float4*)&w[0] = *(const float4*)&Ws[k][n0];
      *(float4*)&w[4] = *(const float4*)&Ws[k][n0 + 4];
#pragma unroll
      for (int i = 0; i < 4; ++i)
#pragma unroll
        for (int j = 0; j < 8; ++j) acc[i][j] = fmaf(a[i], w[j], acc[i][j]);
    }
    __syncthreads();
  }

  float* outp = (seg == 0) ? outM : ((seg == 1) ? outT : outU);
  float bias[8];
  if (seg == 0) {
    *(float4*)&bias[0] = *(const float4*)&Fb[colbase + n0];
    *(float4*)&bias[4] = *(const float4*)&Fb[colbase + n0 + 4];
  }
#pragma unroll
  for (int i = 0; i < 4; ++i) {
    int r = row0 + m0 + i;
    if (r >= nrows) continue;
    float o[8];
#pragma unroll
    for (int j = 0; j < 8; ++j) {
      float v = acc[i][j];
      if (seg == 0) v = fmaxf(v + bias[j], 0.f);
      o[j] = v;
    }
    *(float4*)&outp[(size_t)r * Dc + colbase + n0]     = *(float4*)&o[0];
    *(float4*)&outp[(size_t)r * Dc + colbase + n0 + 4] = *(float4*)&o[4];
  }
}

// ---------------------------------------------------------------------------
// Fused per-(b,c) kernel: e once, E=exp(e-M), both softmax contractions.
//   alpha[s,z] = E/colsum[z]; beta[s,z] = E/rowsum[s]  (exact, shift-invariant)
//   V2[g] = sum_z relu( colrcp[z]*sum_s E[s,z]*Ua[b,s,g] + Tb[cand[z],g] + Gb )
//   V1[g] = sum_s relu( rowrcp[s]*sum_z E[s,z]*Ub[cand[z],g] + Ta[b,s,g] + Gb )
// ---------------------------------------------------------------------------
__global__ __launch_bounds__(512, 4) void fused_kernel(
    const int* __restrict__ cand, const float* __restrict__ Am,
    const float* __restrict__ FBv, const float* __restrict__ Ua,
    const float* __restrict__ Ub, const float* __restrict__ Ta,
    const float* __restrict__ Tb, const float* __restrict__ Gb,
    float* __restrict__ V1, float* __restrict__ V2)
{
  const int bc = blockIdx.x, b = bc >> 6, t = threadIdx.x;

  __shared__ float E[Sc][68];      // 34,816 B, persists
  __shared__ float ubuf[6400];     // 25,600 B union: As+Bs | stats | Ws | red
  __shared__ int   cidx[Zc];
  __shared__ float colrcp[Zc];
  __shared__ float rowrcp[Sc];
  __shared__ float gred[8];

  if (t < Zc) cidx[t] = cand[(size_t)bc * Zc + t];
  __syncthreads();

  // ---------------- phase 1: e = Am[b] (SxD) @ FBc^T (DxZ), tile 4s x 4z ----
  float* As = ubuf;            // [32][132]
  float* Bs = ubuf + 4224;     // [32][68]
  const int s0f = (t & 31) * 4, z0f = (t >> 5) * 4;
  float acc[4][4];
#pragma unroll
  for (int i = 0; i < 4; ++i)
#pragma unroll
    for (int j = 0; j < 4; ++j) acc[i][j] = 0.f;

  for (int k0 = 0; k0 < Dc; k0 += 32) {
#pragma unroll
    for (int i = 0; i < 2; ++i) {
      int f = t + i * 512;
      int sI = f >> 3, kq = f & 7;
      float4 v = *(const float4*)&Am[((size_t)(b * Sc + sI)) * Dc + k0 + kq * 4];
      As[(kq * 4 + 0) * 132 + sI] = v.x;
      As[(kq * 4 + 1) * 132 + sI] = v.y;
      As[(kq * 4 + 2) * 132 + sI] = v.z;
      As[(kq * 4 + 3) * 132 + sI] = v.w;
    }
    {
      int z = t >> 3, kq = t & 7;
      float4 v = *(const float4*)&FBv[(size_t)cidx[z] * Dc + k0 + kq * 4];
      Bs[(kq * 4 + 0) * 68 + z] = v.x;
      Bs[(kq * 4 + 1) * 68 + z] = v.y;
      Bs[(kq * 4 + 2) * 68 + z] = v.z;
      Bs[(kq * 4 + 3) * 68 + z] = v.w;
    }
    __syncthreads();
#pragma unroll
    for (int k = 0; k < 32; ++k) {
      float a4[4], w4[4];
      *(float4*)a4 = *(const float4*)&As[k * 132 + s0f];
      *(float4*)w4 = *(const float4*)&Bs[k * 68 + z0f];
#pragma unroll
      for (int i = 0; i < 4; ++i)
#pragma unroll
        for (int j = 0; j < 4; ++j) acc[i][j] = fmaf(a4[i], w4[j], acc[i][j]);
    }
    __syncthreads();
  }

  // global max (softmax shift) + write E = exp(e - M)
  float m = acc[0][0];
#pragma unroll
  for (int i = 0; i < 4; ++i)
#pragma unroll
    for (int j = 0; j < 4; ++j) m = fmaxf(m, acc[i][j]);
#pragma unroll
  for (int off = 32; off; off >>= 1) m = fmaxf(m, __shfl_xor(m, off));
  if ((t & 63) == 0) gred[t >> 6] = m;
  __syncthreads();
  float M = gred[0];
#pragma unroll
  for (int q = 1; q < 8; ++q) M = fmaxf(M, gred[q]);

#pragma unroll
  for (int i = 0; i < 4; ++i) {
    float4 v;
    v.x = __expf(acc[i][0] - M); v.y = __expf(acc[i][1] - M);
    v.z = __expf(acc[i][2] - M); v.w = __expf(acc[i][3] - M);
    *(float4*)&E[s0f + i][z0f] = v;
  }
  __syncthreads();

  // ---------------- phase 2: colsum/rowsum -> reciprocals -------------------
  float* cs = ubuf;          // [8][64]
  float* rs = ubuf + 512;    // [4][128]
  {
    int z = t & 63, q = t >> 6;
    float s = 0.f;
    for (int i = 0; i < 16; ++i) s += E[q * 16 + i][z];
    cs[q * 64 + z] = s;
  }
  {
    int sI = t & 127, q = t >> 7;
    float s = 0.f;
    for (int i = 0; i < 16; ++i) s += E[sI][q * 16 + i];
    rs[q * 128 + sI] = s;
  }
  __syncthreads();
  if (t < 64) {
    float s = 0.f;
#pragma unroll
    for (int q = 0; q < 8; ++q) s += cs[q * 64 + t];
    colrcp[t] = 1.f / s;
  }
  if (t >= 256 && t < 384) {
    int sI = t - 256;
    rowrcp[sI] = 1.f / (rs[sI] + rs[128 + sI] + rs[256 + sI] + rs[384 + sI]);
  }
  __syncthreads();

  // common epilogue constants
  const int g0 = (t & 31) * 4;   // columns {g0..g0+3} and {128+g0..+3}
  float gb[8];
  *(float4*)&gb[0] = *(const float4*)&Gb[g0];
  *(float4*)&gb[4] = *(const float4*)&Gb[128 + g0];

  float* Ws  = ubuf;   // [16][264] staged W chunk
  float* red = ubuf;   // [16][256] reduction (aliases Ws, time-disjoint)

  // ---------------- phase 3a: V2 (P2 = E^T @ Ua, tile 4z x 8g) --------------
  {
    const int zz0 = (t >> 5) * 4;
    float acc2[4][8];
#pragma unroll
    for (int i = 0; i < 4; ++i)
#pragma unroll
      for (int j = 0; j < 8; ++j) acc2[i][j] = 0.f;

    for (int sc = 0; sc < 8; ++sc) {
#pragma unroll
      for (int i = 0; i < 2; ++i) {
        int f = t + i * 512;
        int r = f >> 6, c = (f & 63) * 4;
        *(float4*)&Ws[r * 264 + c] =
            *(const float4*)&Ua[((size_t)(b * Sc + sc * 16 + r)) * Dc + c];
      }
      __syncthreads();
#pragma unroll
      for (int k = 0; k < 16; ++k) {
        float al[4], ulo[4], uhi[4];
        *(float4*)al  = *(const float4*)&E[sc * 16 + k][zz0];
        *(float4*)ulo = *(const float4*)&Ws[k * 264 + g0];
        *(float4*)uhi = *(const float4*)&Ws[k * 264 + 128 + g0];
#pragma unroll
        for (int i = 0; i < 4; ++i)
#pragma unroll
          for (int j = 0; j < 4; ++j) {
            acc2[i][j]     = fmaf(al[i], ulo[j], acc2[i][j]);
            acc2[i][j + 4] = fmaf(al[i], uhi[j], acc2[i][j + 4]);
          }
      }
      __syncthreads();
    }
    float sv[8] = {0.f, 0.f, 0.f, 0.f, 0.f, 0.f, 0.f, 0.f};
#pragma unroll
    for (int zi = 0; zi < 4; ++zi) {
      int z = zz0 + zi;
      float cr = colrcp[z];
      const float* tp = &Tb[(size_t)cidx[z] * Dc];
      float tlo[4], thi[4];
      *(float4*)tlo = *(const float4*)&tp[g0];
      *(float4*)thi = *(const float4*)&tp[128 + g0];
#pragma unroll
      for (int j = 0; j < 4; ++j) {
        sv[j]     += fmaxf(fmaf(acc2[zi][j],     cr, tlo[j] + gb[j]),     0.f);
        sv[j + 4] += fmaxf(fmaf(acc2[zi][j + 4], cr, thi[j] + gb[j + 4]), 0.f);
      }
    }
    *(float4*)&red[(t >> 5) * 256 + g0]       = *(float4*)&sv[0];
    *(float4*)&red[(t >> 5) * 256 + 128 + g0] = *(float4*)&sv[4];
    __syncthreads();
    if (t < 256) {
      float s = 0.f;
#pragma unroll
      for (int q = 0; q < 16; ++q) s += red[q * 256 + t];
      V2[(size_t)bc * Dc + t] = s;
    }
    __syncthreads();
  }

  // ---------------- phase 3b: V1 (P1 = E @ Ub, tile 4s x 8g, 2 passes) ------
  {
    const int sg = t >> 5;    // 0..15
    float v1tot = 0.f;
    for (int p = 0; p < 2; ++p) {
      const int s0 = p * 64 + sg * 4;
      float acc1[4][8];
#pragma unroll
      for (int i = 0; i < 4; ++i)
#pragma unroll
        for (int j = 0; j < 8; ++j) acc1[i][j] = 0.f;

      for (int zc = 0; zc < 4; ++zc) {
#pragma unroll
        for (int i = 0; i < 2; ++i) {
          int f = t + i * 512;
          int r = f >> 6, c = (f & 63) * 4;
          *(float4*)&Ws[r * 264 + c] =
              *(const float4*)&Ub[(size_t)cidx[zc * 16 + r] * Dc + c];
        }
        __syncthreads();
#pragma unroll
        for (int k4 = 0; k4 < 4; ++k4) {
          float e4[4][4];
#pragma unroll
          for (int i = 0; i < 4; ++i)
            *(float4*)e4[i] = *(const float4*)&E[s0 + i][zc * 16 + k4 * 4];
#pragma unroll
          for (int zj = 0; zj < 4; ++zj) {
            float ulo[4], uhi[4];
            *(float4*)ulo = *(const float4*)&Ws[(k4 * 4 + zj) * 264 + g0];
            *(float4*)uhi = *(const float4*)&Ws[(k4 * 4 + zj) * 264 + 128 + g0];
#pragma unroll
            for (int i = 0; i < 4; ++i)
#pragma unroll
              for (int j = 0; j < 4; ++j) {
                acc1[i][j]     = fmaf(e4[i][zj], ulo[j], acc1[i][j]);
                acc1[i][j + 4] = fmaf(e4[i][zj], uhi[j], acc1[i][j + 4]);
              }
          }
        }
        __syncthreads();
      }
      float sv[8] = {0.f, 0.f, 0.f, 0.f, 0.f, 0.f, 0.f, 0.f};
#pragma unroll
      for (int i = 0; i < 4; ++i) {
        float rr = rowrcp[s0 + i];
        const float* tp = &Ta[((size_t)(b * Sc + s0 + i)) * Dc];
        float tlo[4], thi[4];
        *(float4*)tlo = *(const float4*)&tp[g0];
        *(float4*)thi = *(const float4*)&tp[128 + g0];
#pragma unroll
        for (int j = 0; j < 4; ++j) {
          sv[j]     += fmaxf(fmaf(acc1[i][j],     rr, tlo[j] + gb[j]),     0.f);
          sv[j + 4] += fmaxf(fmaf(acc1[i][j + 4], rr, thi[j] + gb[j + 4]), 0.f);
        }
      }
      *(float4*)&red[sg * 256 + g0]       = *(float4*)&sv[0];
      *(float4*)&red[sg * 256 + 128 + g0] = *(float4*)&sv[4];
      __syncthreads();
      if (t < 256) {
        float s = 0.f;
#pragma unroll
        for (int q = 0; q < 16; ++q) s += red[q * 256 + t];
        v1tot += s;
      }
      __syncthreads();
    }
    if (t < 256) V1[(size_t)bc * Dc + t] = v1tot;
  }
}

// ---------------------------------------------------------------------------
// K7: y[bc] = V1[bc]·HW[0:256] + V2[bc]·HW[256:512] + Hb
// ---------------------------------------------------------------------------
__global__ __launch_bounds__(256) void final_kernel(
    const float* __restrict__ V1, const float* __restrict__ V2,
    const float* __restrict__ HW, const float* __restrict__ Hb,
    float* __restrict__ y)
{
  const int t = threadIdx.x;
  const int w = t >> 6, l = t & 63;
  const int bc = blockIdx.x * 4 + w;
  float4 v1 = *(const float4*)&V1[(size_t)bc * Dc + l * 4];
  float4 h1 = *(const float4*)&HW[l * 4];
  float4 v2 = *(const float4*)&V2[(size_t)bc * Dc + l * 4];
  float4 h2 = *(const float4*)&HW[Dc + l * 4];
  float sum = v1.x * h1.x + v1.y * h1.y + v1.z * h1.z + v1.w * h1.w
            + v2.x * h2.x + v2.y * h2.y + v2.z * h2.z + v2.w * h2.w;
#pragma unroll
  for (int off = 32; off > 0; off >>= 1) sum += __shfl_down(sum, off);
  if (l == 0) y[bc] = sum + Hb[0];
}

extern "C" void kernel_launch(void* const* d_in, const int* in_sizes, int n_in,
                              void* d_out, int out_size, void* d_ws, size_t ws_size,
                              hipStream_t stream) {
  (void)in_sizes; (void)n_in; (void)out_size; (void)ws_size;
  const int*   inp  = (const int*)d_in[0];
  const int*   cand = (const int*)d_in[1];
  const float* EmbA = (const float*)d_in[4];
  const float* EmbB = (const float*)d_in[5];
  const float* FW   = (const float*)d_in[6];
  const float* Fb   = (const float*)d_in[7];
  const float* GW   = (const float*)d_in[8];
  const float* Gb   = (const float*)d_in[9];
  const float* HW   = (const float*)d_in[10];
  const float* Hb   = (const float*)d_in[11];
  float* y = (float*)d_out;

  float* ws = (float*)d_ws;
  const size_t nA = (size_t)Bc * Sc * Dc;   // 1,048,576
  const size_t nB = (size_t)VOc * Dc;       // 1,280,000
  const size_t nV = (size_t)Bc * Cc * Dc;   //   524,288
  float* Am  = ws;
  float* Ta  = Am + nA;
  float* Ua  = Ta + nA;
  float* FBv = Ua + nA;
  float* Tb  = FBv + nB;
  float* Ub  = Tb + nB;
  float* V1  = Ub + nB;
  float* V2  = V1 + nV;

  transform_kernel<<<dim3((Bc * Sc) / 64, 6), 256, 0, stream>>>(
      EmbA, inp, Bc * Sc, FW, Fb, GW, Am, Ta, Ua);
  transform_kernel<<<dim3((VOc + 63) / 64, 6), 256, 0, stream>>>(
      EmbB, nullptr, VOc, FW, Fb, GW, FBv, Tb, Ub);
  fused_kernel<<<Bc * Cc, 512, 0, stream>>>(cand, Am, FBv, Ua, Ub, Ta, Tb, Gb, V1, V2);
  final_kernel<<<(Bc * Cc) / 4, 256, 0, stream>>>(V1, V2, HW, Hb, y);
}

// Round 3
// 492.705 us; speedup vs baseline: 1.8070x; 1.0103x over previous
//
#include <hip/hip_runtime.h>
#include <hip/hip_bf16.h>
#include <math.h>

#define Bc 32
#define Cc 64
#define Sc 128
#define Zc 64
#define Dc 256
#define VOc 5000

typedef __attribute__((ext_vector_type(8))) short v8s;   // 8 bf16 = 4 VGPR MFMA frag
typedef __attribute__((ext_vector_type(4))) float f4;    // 16x16 accum

union FQ { uint4 q; v8s s; };

struct HL { v8s hi, lo; };

__device__ __forceinline__ unsigned short bf_bits(__hip_bfloat16 h) {
  union { __hip_bfloat16 b; unsigned short u; } cv; cv.b = h; return cv.u;
}

// pack fp32 -> (hi bf16 | lo bf16 << 16), hi+lo ~= x to ~2^-16 rel
__device__ __forceinline__ unsigned pack_hl(float x) {
  __hip_bfloat16 h = __float2bfloat16(x);
  float hf = __bfloat162float(h);
  __hip_bfloat16 l = __float2bfloat16(x - hf);
  return (unsigned)bf_bits(h) | ((unsigned)bf_bits(l) << 16);
}

// 8 packed u32 -> hi-frag + lo-frag (v_perm byte shuffles)
__device__ __forceinline__ HL unpack8(uint4 q0, uint4 q1) {
  FQ h, l;
  h.q.x = __builtin_amdgcn_perm(q0.y, q0.x, 0x05040100u);
  h.q.y = __builtin_amdgcn_perm(q0.w, q0.z, 0x05040100u);
  h.q.z = __builtin_amdgcn_perm(q1.y, q1.x, 0x05040100u);
  h.q.w = __builtin_amdgcn_perm(q1.w, q1.z, 0x05040100u);
  l.q.x = __builtin_amdgcn_perm(q0.y, q0.x, 0x07060302u);
  l.q.y = __builtin_amdgcn_perm(q0.w, q0.z, 0x07060302u);
  l.q.z = __builtin_amdgcn_perm(q1.y, q1.x, 0x07060302u);
  l.q.w = __builtin_amdgcn_perm(q1.w, q1.z, 0x07060302u);
  HL r; r.hi = h.s; r.lo = l.s; return r;
}

// 3-term split product: (Ah+Al)(Bh+Bl) ~= AhBh + AhBl + AlBh (fp32 accum)
__device__ __forceinline__ f4 mm3(const HL& a, const HL& b, f4 c) {
  c = __builtin_amdgcn_mfma_f32_16x16x32_bf16(a.hi, b.hi, c, 0, 0, 0);
  c = __builtin_amdgcn_mfma_f32_16x16x32_bf16(a.hi, b.lo, c, 0, 0, 0);
  c = __builtin_amdgcn_mfma_f32_16x16x32_bf16(a.lo, b.hi, c, 0, 0, 0);
  return c;
}

// ---------------------------------------------------------------------------
// Merged transform: blocks [0,64) -> EmbA task (4096 rows, gathered by inp),
// blocks [64,143) -> EmbB task (5000 rows, identity).
//  seg0: relu(row@FW+Fb) -> packed hi/lo  (Am_hl | FB_hl)
//  seg1: row@GW[0:256]   -> fp32          (Ta | Tb)
//  seg2: row@GW[256:512] -> packed hi/lo  (UaT transposed [b][g][s] | Ub_hl)
// ---------------------------------------------------------------------------
__global__ __launch_bounds__(256) void transform_kernel(
    const float* __restrict__ EmbA, const int* __restrict__ inp,
    const float* __restrict__ EmbB,
    const float* __restrict__ FW, const float* __restrict__ Fb,
    const float* __restrict__ GW,
    unsigned* __restrict__ Am_hl, float* __restrict__ Ta, unsigned* __restrict__ UaT,
    unsigned* __restrict__ FB_hl, float* __restrict__ Tb, unsigned* __restrict__ Ub_hl)
{
  const bool taskA = (blockIdx.x < 64);
  const int rb = taskA ? blockIdx.x : (blockIdx.x - 64);
  const int nrows = taskA ? 4096 : 5000;
  const float* __restrict__ Emb = taskA ? EmbA : EmbB;
  const int* __restrict__ idx = taskA ? inp : nullptr;

  const int cb = blockIdx.y;
  const int row0 = rb * 64;
  const int seg = cb >> 1;               // 0:FW 1:GW1 2:GW2
  const int colbase = (cb & 1) * 128;
  const float* W = (seg == 0) ? FW : GW;
  const int rowoff = (seg == 2) ? Dc : 0;

  __shared__ float As[32][68];
  __shared__ float Ws[32][132];

  const int t = threadIdx.x;
  const int mt = t >> 4, nt = t & 15;
  const int m0 = mt * 4, n0 = nt * 8;
  float acc[4][8];
#pragma unroll
  for (int i = 0; i < 4; ++i)
#pragma unroll
    for (int j = 0; j < 8; ++j) acc[i][j] = 0.f;

  for (int k0 = 0; k0 < Dc; k0 += 32) {
#pragma unroll
    for (int i = 0; i < 2; ++i) {
      int f = t + i * 256;
      int m = f >> 3, kq = f & 7;
      int r = row0 + m; if (r > nrows - 1) r = nrows - 1;
      int src = idx ? idx[r] : r;
      float4 v = *(const float4*)&Emb[(size_t)src * Dc + k0 + kq * 4];
      As[kq * 4 + 0][m] = v.x; As[kq * 4 + 1][m] = v.y;
      As[kq * 4 + 2][m] = v.z; As[kq * 4 + 3][m] = v.w;
    }
#pragma unroll
    for (int i = 0; i < 4; ++i) {
      int f = t + i * 256;
      int k = f >> 5, nq = f & 31;
      float4 v = *(const float4*)&W[(size_t)(rowoff + k0 + k) * Dc + colbase + nq * 4];
      *(float4*)&Ws[k][nq * 4] = v;
    }
    __syncthreads();
#pragma unroll
    for (int k = 0; k < 32; ++k) {
      float a[4], w[8];
      *(float4*)&a[0] = *(const float4*)&As[k][m0];
      *(float4*)&w[0] = *(const float4*)&Ws[k][n0];
      *(float4*)&w[4] = *(const float4*)&Ws[k][n0 + 4];
#pragma unroll
      for (int i = 0; i < 4; ++i)
#pragma unroll
        for (int j = 0; j < 8; ++j) acc[i][j] = fmaf(a[i], w[j], acc[i][j]);
    }
    __syncthreads();
  }

  if (seg == 1) {
    float* outp = taskA ? Ta : Tb;
#pragma unroll
    for (int i = 0; i < 4; ++i) {
      int r = row0 + m0 + i;
      if (r >= nrows) continue;
      *(float4*)&outp[(size_t)r * Dc + colbase + n0]     = *(float4*)&acc[i][0];
      *(float4*)&outp[(size_t)r * Dc + colbase + n0 + 4] = *(float4*)&acc[i][4];
    }
  } else {
    float bias[8];
    if (seg == 0) {
#pragma unroll
      for (int j = 0; j < 8; ++j) bias[j] = Fb[colbase + n0 + j];
    }
#pragma unroll
    for (int i = 0; i < 4; ++i) {
      int r = row0 + m0 + i;
      if (r >= nrows) continue;
      unsigned pk[8];
#pragma unroll
      for (int j = 0; j < 8; ++j) {
        float v = acc[i][j];
        if (seg == 0) v = fmaxf(v + bias[j], 0.f);
        pk[j] = pack_hl(v);
      }
      if (seg == 0) {
        unsigned* o = taskA ? Am_hl : FB_hl;
        *(uint4*)&o[(size_t)r * Dc + colbase + n0]     = *(uint4*)&pk[0];
        *(uint4*)&o[(size_t)r * Dc + colbase + n0 + 4] = *(uint4*)&pk[4];
      } else if (!taskA) {
        *(uint4*)&Ub_hl[(size_t)r * Dc + colbase + n0]     = *(uint4*)&pk[0];
        *(uint4*)&Ub_hl[(size_t)r * Dc + colbase + n0 + 4] = *(uint4*)&pk[4];
      } else {
        // transposed: UaT[b][g][s]
        int bI = r >> 7, sI = r & 127;
#pragma unroll
        for (int j = 0; j < 8; ++j)
          UaT[((size_t)(bI * 256 + colbase + n0 + j)) * 128 + sI] = pk[j];
      }
    }
  }
}

// ---------------------------------------------------------------------------
// Fused per-(b,c) MFMA kernel.
// LDS (dynamic, 144416 B): E[s][z], Et[z][s], UbT[g][z] (all packed hi|lo u32,
// XOR-swizzled), + stats/reduction scratch.
// ---------------------------------------------------------------------------
#define E_STR  68
#define ET_STR 132
#define UB_STR 68
#define SMEM_BYTES ((128*E_STR + 64*ET_STR + 256*UB_STR + 256 + 64 + 128 + 512 + 512 + 64 + 8) * 4)

__device__ __forceinline__ int ea(int s, int z)  { return s * E_STR  + (z ^ ((s & 3) << 3)); }
__device__ __forceinline__ int eta(int z, int s) { return z * ET_STR + (s ^ ((z & 3) << 3)); }
__device__ __forceinline__ int uba(int g, int z) { return g * UB_STR + (z ^ ((g & 3) << 3)); }

__global__ __launch_bounds__(512, 2) void fused_kernel(
    const int* __restrict__ cand,
    const unsigned* __restrict__ Am_hl, const unsigned* __restrict__ FB_hl,
    const unsigned* __restrict__ UaT, const unsigned* __restrict__ Ub_hl,
    const float* __restrict__ Ta, const float* __restrict__ Tb,
    const float* __restrict__ Gb,
    float* __restrict__ V1, float* __restrict__ V2)
{
  extern __shared__ char smem[];
  unsigned* E    = (unsigned*)smem;          // 128*68
  unsigned* Et   = E + 128 * E_STR;          // 64*132
  unsigned* Ub   = Et + 64 * ET_STR;         // 256*68
  float* gbL     = (float*)(Ub + 256 * UB_STR); // 256
  float* crcp    = gbL + 256;                // 64
  float* rrcp    = crcp + 64;                // 128
  float* csp     = rrcp + 128;               // 8*64
  float* vred    = csp + 512;                // 2*256
  int*   cidx    = (int*)(vred + 512);       // 64
  float* gmax    = (float*)(cidx + 64);      // 8

  const int bc = blockIdx.x, b = bc >> 6, t = threadIdx.x;
  const int w = t >> 6, l = t & 63, a = l & 15, hq = l >> 4;

  if (t < 64) cidx[t] = cand[(size_t)bc * 64 + t];
  if (t >= 256) gbL[t - 256] = Gb[t - 256];
  __syncthreads();

  // ---- stage gathered Ub rows into LDS as UbT[g][z] (packed) ----
#pragma unroll 4
  for (int it = 0; it < 32; ++it) {
    int flat = it * 512 + t;                 // 16384 = 64 z * 256 g
    int z = flat >> 8, g = flat & 255;
    Ub[uba(g, z)] = Ub_hl[(size_t)cidx[z] * 256 + g];
  }

  // ---- phase 1: e = Am[b] @ FBc^T ; wave w owns s-tile w, all 4 z-tiles ----
  f4 acc[4];
#pragma unroll
  for (int zt = 0; zt < 4; ++zt)
#pragma unroll
    for (int r = 0; r < 4; ++r) acc[zt][r] = 0.f;

  {
    const unsigned* ap = Am_hl + ((size_t)(b * 128 + w * 16 + a)) * 256;
    int crow[4];
#pragma unroll
    for (int zt = 0; zt < 4; ++zt) crow[zt] = cidx[zt * 16 + a];
#pragma unroll
    for (int ch = 0; ch < 8; ++ch) {
      int k0 = ch * 32 + hq * 8;
      HL A = unpack8(*(const uint4*)(ap + k0), *(const uint4*)(ap + k0 + 4));
#pragma unroll
      for (int zt = 0; zt < 4; ++zt) {
        const unsigned* bp = FB_hl + (size_t)crow[zt] * 256 + k0;
        HL B = unpack8(*(const uint4*)bp, *(const uint4*)(bp + 4));
        acc[zt] = mm3(A, B, acc[zt]);
      }
    }
  }

  // ---- softmax: global max -> E=exp(e-M); rowsum/colsum -> reciprocals ----
  {
    float m = -1e30f;
#pragma unroll
    for (int zt = 0; zt < 4; ++zt)
#pragma unroll
      for (int r = 0; r < 4; ++r) m = fmaxf(m, acc[zt][r]);
#pragma unroll
    for (int d = 1; d < 64; d <<= 1) m = fmaxf(m, __shfl_xor(m, d));
    if (l == 0) gmax[w] = m;
    __syncthreads();
    float M = gmax[0];
#pragma unroll
    for (int q = 1; q < 8; ++q) M = fmaxf(M, gmax[q]);

#pragma unroll
    for (int zt = 0; zt < 4; ++zt)
#pragma unroll
      for (int r = 0; r < 4; ++r) acc[zt][r] = __expf(acc[zt][r] - M);

    // rowsum over all 64 z (this wave holds full rows)
#pragma unroll
    for (int r = 0; r < 4; ++r) {
      float rs = acc[0][r] + acc[1][r] + acc[2][r] + acc[3][r];
      rs += __shfl_xor(rs, 1); rs += __shfl_xor(rs, 2);
      rs += __shfl_xor(rs, 4); rs += __shfl_xor(rs, 8);
      if (a == 0) rrcp[w * 16 + hq * 4 + r] = 1.f / rs;
    }
    // colsum partial (this wave's 16 rows)
#pragma unroll
    for (int zt = 0; zt < 4; ++zt) {
      float c = acc[zt][0] + acc[zt][1] + acc[zt][2] + acc[zt][3];
      c += __shfl_xor(c, 16); c += __shfl_xor(c, 32);
      if (l < 16) csp[w * 64 + zt * 16 + l] = c;
    }
    // pack + store E both orientations
#pragma unroll
    for (int zt = 0; zt < 4; ++zt)
#pragma unroll
      for (int r = 0; r < 4; ++r) {
        int s = w * 16 + hq * 4 + r, z = zt * 16 + a;
        unsigned pk = pack_hl(acc[zt][r]);
        E[ea(s, z)] = pk;
        Et[eta(z, s)] = pk;
      }
    __syncthreads();
    if (t < 64) {
      float s = 0.f;
#pragma unroll
      for (int q = 0; q < 8; ++q) s += csp[q * 64 + t];
      crcp[t] = 1.f / s;
    }
    __syncthreads();
  }

  // ---- phase 3a: P2 = Et @ Ua ; V2 = sum_z relu(P2*crcp + Tb + Gb) ----
  {
    const int ztg = w >> 2, gtg = w & 3;   // wave: 2 z-tiles x 4 g-tiles
    HL af[2][4];
#pragma unroll
    for (int zt2 = 0; zt2 < 2; ++zt2) {
      int z = (ztg * 2 + zt2) * 16 + a;
#pragma unroll
      for (int ch = 0; ch < 4; ++ch) {
        int ad = eta(z, ch * 32 + hq * 8);
        af[zt2][ch] = unpack8(*(const uint4*)(Et + ad), *(const uint4*)(Et + ad + 4));
      }
    }
    f4 acc2[2][4];
#pragma unroll
    for (int i = 0; i < 2; ++i)
#pragma unroll
      for (int j = 0; j < 4; ++j)
#pragma unroll
        for (int r = 0; r < 4; ++r) acc2[i][j][r] = 0.f;

#pragma unroll
    for (int gt2 = 0; gt2 < 4; ++gt2) {
      int g = gtg * 64 + gt2 * 16 + a;
      const unsigned* bp = UaT + ((size_t)(b * 256 + g)) * 128;
#pragma unroll
      for (int ch = 0; ch < 4; ++ch) {
        int s0 = ch * 32 + hq * 8;
        HL B = unpack8(*(const uint4*)(bp + s0), *(const uint4*)(bp + s0 + 4));
        acc2[0][gt2] = mm3(af[0][ch], B, acc2[0][gt2]);
        acc2[1][gt2] = mm3(af[1][ch], B, acc2[1][gt2]);
      }
    }
#pragma unroll
    for (int gt2 = 0; gt2 < 4; ++gt2) {
      int g = gtg * 64 + gt2 * 16 + a;
      float gb = gbL[g];
      float sv = 0.f;
#pragma unroll
      for (int zt2 = 0; zt2 < 2; ++zt2) {
#pragma unroll
        for (int r = 0; r < 4; ++r) {
          int z = (ztg * 2 + zt2) * 16 + hq * 4 + r;
          float v = fmaf(acc2[zt2][gt2][r], crcp[z],
                         Tb[(size_t)cidx[z] * 256 + g] + gb);
          sv += fmaxf(v, 0.f);
        }
      }
      sv += __shfl_xor(sv, 16); sv += __shfl_xor(sv, 32);
      if (l < 16) vred[ztg * 256 + g] = sv;
    }
    __syncthreads();
    if (t < 256) V2[(size_t)bc * 256 + t] = vred[t] + vred[256 + t];
    __syncthreads();
  }

  // ---- phase 3b: P1 = E @ UbT ; V1 = sum_s relu(P1*rrcp + Ta + Gb) ----
  {
    const int stg = w >> 2, gtg = w & 3;   // wave: 4 s-tiles x 4 g-tiles
    HL af[4][2];
#pragma unroll
    for (int st2 = 0; st2 < 4; ++st2) {
      int s = (stg * 4 + st2) * 16 + a;
#pragma unroll
      for (int ch = 0; ch < 2; ++ch) {
        int ad = ea(s, ch * 32 + hq * 8);
        af[st2][ch] = unpack8(*(const uint4*)(E + ad), *(const uint4*)(E + ad + 4));
      }
    }
    f4 acc1[4][4];
#pragma unroll
    for (int i = 0; i < 4; ++i)
#pragma unroll
      for (int j = 0; j < 4; ++j)
#pragma unroll
        for (int r = 0; r < 4; ++r) acc1[i][j][r] = 0.f;

#pragma unroll
    for (int gt2 = 0; gt2 < 4; ++gt2) {
      int g = gtg * 64 + gt2 * 16 + a;
#pragma unroll
      for (int ch = 0; ch < 2; ++ch) {
        int ad = uba(g, ch * 32 + hq * 8);
        HL B = unpack8(*(const uint4*)(Ub + ad), *(const uint4*)(Ub + ad + 4));
#pragma unroll
        for (int st2 = 0; st2 < 4; ++st2)
          acc1[st2][gt2] = mm3(af[st2][ch], B, acc1[st2][gt2]);
      }
    }
#pragma unroll
    for (int gt2 = 0; gt2 < 4; ++gt2) {
      int g = gtg * 64 + gt2 * 16 + a;
      float gb = gbL[g];
      float sv = 0.f;
#pragma unroll
      for (int st2 = 0; st2 < 4; ++st2) {
#pragma unroll
        for (int r = 0; r < 4; ++r) {
          int s = (stg * 4 + st2) * 16 + hq * 4 + r;
          float v = fmaf(acc1[st2][gt2][r], rrcp[s],
                         Ta[((size_t)(b * 128 + s)) * 256 + g] + gb);
          sv += fmaxf(v, 0.f);
        }
      }
      sv += __shfl_xor(sv, 16); sv += __shfl_xor(sv, 32);
      if (l < 16) vred[stg * 256 + g] = sv;
    }
    __syncthreads();
    if (t < 256) V1[(size_t)bc * 256 + t] = vred[t] + vred[256 + t];
  }
}

// ---------------------------------------------------------------------------
// y[bc] = V1[bc]·HW[0:256] + V2[bc]·HW[256:512] + Hb
// ---------------------------------------------------------------------------
__global__ __launch_bounds__(256) void final_kernel(
    const float* __restrict__ V1, const float* __restrict__ V2,
    const float* __restrict__ HW, const float* __restrict__ Hb,
    float* __restrict__ y)
{
  const int t = threadIdx.x;
  const int w = t >> 6, l = t & 63;
  const int bc = blockIdx.x * 4 + w;
  float4 v1 = *(const float4*)&V1[(size_t)bc * Dc + l * 4];
  float4 h1 = *(const float4*)&HW[l * 4];
  float4 v2 = *(const float4*)&V2[(size_t)bc * Dc + l * 4];
  float4 h2 = *(const float4*)&HW[Dc + l * 4];
  float sum = v1.x * h1.x + v1.y * h1.y + v1.z * h1.z + v1.w * h1.w
            + v2.x * h2.x + v2.y * h2.y + v2.z * h2.z + v2.w * h2.w;
#pragma unroll
  for (int off = 32; off > 0; off >>= 1) sum += __shfl_down(sum, off);
  if (l == 0) y[bc] = sum + Hb[0];
}

extern "C" void kernel_launch(void* const* d_in, const int* in_sizes, int n_in,
                              void* d_out, int out_size, void* d_ws, size_t ws_size,
                              hipStream_t stream) {
  (void)in_sizes; (void)n_in; (void)out_size; (void)ws_size;
  const int*   inp  = (const int*)d_in[0];
  const int*   cand = (const int*)d_in[1];
  const float* EmbA = (const float*)d_in[4];
  const float* EmbB = (const float*)d_in[5];
  const float* FW   = (const float*)d_in[6];
  const float* Fb   = (const float*)d_in[7];
  const float* GW   = (const float*)d_in[8];
  const float* Gb   = (const float*)d_in[9];
  const float* HW   = (const float*)d_in[10];
  const float* Hb   = (const float*)d_in[11];
  float* y = (float*)d_out;

  const size_t nA = (size_t)Bc * Sc * Dc;   // 1,048,576
  const size_t nB = (size_t)VOc * Dc;       // 1,280,000
  const size_t nV = (size_t)Bc * Cc * Dc;   //   524,288
  unsigned* Am_hl = (unsigned*)d_ws;
  float*    Ta    = (float*)(Am_hl + nA);
  unsigned* UaT   = (unsigned*)(Ta + nA);
  unsigned* FB_hl = UaT + nA;               // Ua transposed is 32*256*128 = nA
  float*    Tb    = (float*)(FB_hl + nB);
  unsigned* Ub_hl = (unsigned*)(Tb + nB);
  float*    V1    = (float*)(Ub_hl + nB);
  float*    V2    = V1 + nV;                // total ~32.1 MB

  hipFuncSetAttribute((const void*)fused_kernel,
                      hipFuncAttributeMaxDynamicSharedMemorySize, SMEM_BYTES);

  transform_kernel<<<dim3(143, 6), 256, 0, stream>>>(
      EmbA, inp, EmbB, FW, Fb, GW, Am_hl, Ta, UaT, FB_hl, Tb, Ub_hl);
  fused_kernel<<<Bc * Cc, 512, SMEM_BYTES, stream>>>(
      cand, Am_hl, FB_hl, UaT, Ub_hl, Ta, Tb, Gb, V1, V2);
  final_kernel<<<(Bc * Cc) / 4, 256, 0, stream>>>(V1, V2, HW, Hb, y);
}

// Round 4
// 377.169 us; speedup vs baseline: 2.3605x; 1.3063x over previous
//
#include <hip/hip_runtime.h>
#include <hip/hip_bf16.h>
#include <math.h>

#define Bc 32
#define Cc 64
#define Sc 128
#define Zc 64
#define Dc 256
#define VOc 5000

typedef __attribute__((ext_vector_type(8))) short v8s;   // 8 bf16 = 4 VGPR MFMA frag
typedef __attribute__((ext_vector_type(4))) float f4;    // 16x16 accum

union FQ { uint4 q; v8s s; };

struct HL { v8s hi, lo; };

__device__ __forceinline__ unsigned short bf_bits(__hip_bfloat16 h) {
  union { __hip_bfloat16 b; unsigned short u; } cv; cv.b = h; return cv.u;
}

// pack fp32 -> (hi bf16 | lo bf16 << 16), hi+lo ~= x to ~2^-16 rel
__device__ __forceinline__ unsigned pack_hl(float x) {
  __hip_bfloat16 h = __float2bfloat16(x);
  float hf = __bfloat162float(h);
  __hip_bfloat16 l = __float2bfloat16(x - hf);
  return (unsigned)bf_bits(h) | ((unsigned)bf_bits(l) << 16);
}

// 8 packed u32 -> hi-frag + lo-frag (v_perm byte shuffles)
__device__ __forceinline__ HL unpack8(uint4 q0, uint4 q1) {
  FQ h, l;
  h.q.x = __builtin_amdgcn_perm(q0.y, q0.x, 0x05040100u);
  h.q.y = __builtin_amdgcn_perm(q0.w, q0.z, 0x05040100u);
  h.q.z = __builtin_amdgcn_perm(q1.y, q1.x, 0x05040100u);
  h.q.w = __builtin_amdgcn_perm(q1.w, q1.z, 0x05040100u);
  l.q.x = __builtin_amdgcn_perm(q0.y, q0.x, 0x07060302u);
  l.q.y = __builtin_amdgcn_perm(q0.w, q0.z, 0x07060302u);
  l.q.z = __builtin_amdgcn_perm(q1.y, q1.x, 0x07060302u);
  l.q.w = __builtin_amdgcn_perm(q1.w, q1.z, 0x07060302u);
  HL r; r.hi = h.s; r.lo = l.s; return r;
}

// 3-term split product: (Ah+Al)(Bh+Bl) ~= AhBh + AhBl + AlBh (fp32 accum)
__device__ __forceinline__ f4 mm3(const HL& a, const HL& b, f4 c) {
  c = __builtin_amdgcn_mfma_f32_16x16x32_bf16(a.hi, b.hi, c, 0, 0, 0);
  c = __builtin_amdgcn_mfma_f32_16x16x32_bf16(a.hi, b.lo, c, 0, 0, 0);
  c = __builtin_amdgcn_mfma_f32_16x16x32_bf16(a.lo, b.hi, c, 0, 0, 0);
  return c;
}

// ---------------------------------------------------------------------------
// Merged transform: blocks [0,64) -> EmbA task (4096 rows, gathered by inp),
// blocks [64,143) -> EmbB task (5000 rows, identity).
//  seg0: relu(row@FW+Fb) -> packed hi/lo  (Am_hl | FB_hl)
//  seg1: row@GW[0:256]   -> fp32          (Ta | Tb)
//  seg2: row@GW[256:512] -> packed hi/lo  (UaT transposed [b][g][s] | Ub_hl)
// ---------------------------------------------------------------------------
__global__ __launch_bounds__(256) void transform_kernel(
    const float* __restrict__ EmbA, const int* __restrict__ inp,
    const float* __restrict__ EmbB,
    const float* __restrict__ FW, const float* __restrict__ Fb,
    const float* __restrict__ GW,
    unsigned* __restrict__ Am_hl, float* __restrict__ Ta, unsigned* __restrict__ UaT,
    unsigned* __restrict__ FB_hl, float* __restrict__ Tb, unsigned* __restrict__ Ub_hl)
{
  const bool taskA = (blockIdx.x < 64);
  const int rb = taskA ? blockIdx.x : (blockIdx.x - 64);
  const int nrows = taskA ? 4096 : 5000;
  const float* __restrict__ Emb = taskA ? EmbA : EmbB;
  const int* __restrict__ idx = taskA ? inp : nullptr;

  const int cb = blockIdx.y;
  const int row0 = rb * 64;
  const int seg = cb >> 1;               // 0:FW 1:GW1 2:GW2
  const int colbase = (cb & 1) * 128;
  const float* W = (seg == 0) ? FW : GW;
  const int rowoff = (seg == 2) ? Dc : 0;

  __shared__ float As[32][68];
  __shared__ float Ws[32][132];

  const int t = threadIdx.x;
  const int mt = t >> 4, nt = t & 15;
  const int m0 = mt * 4, n0 = nt * 8;
  float acc[4][8];
#pragma unroll
  for (int i = 0; i < 4; ++i)
#pragma unroll
    for (int j = 0; j < 8; ++j) acc[i][j] = 0.f;

  for (int k0 = 0; k0 < Dc; k0 += 32) {
#pragma unroll
    for (int i = 0; i < 2; ++i) {
      int f = t + i * 256;
      int m = f >> 3, kq = f & 7;
      int r = row0 + m; if (r > nrows - 1) r = nrows - 1;
      int src = idx ? idx[r] : r;
      float4 v = *(const float4*)&Emb[(size_t)src * Dc + k0 + kq * 4];
      As[kq * 4 + 0][m] = v.x; As[kq * 4 + 1][m] = v.y;
      As[kq * 4 + 2][m] = v.z; As[kq * 4 + 3][m] = v.w;
    }
#pragma unroll
    for (int i = 0; i < 4; ++i) {
      int f = t + i * 256;
      int k = f >> 5, nq = f & 31;
      float4 v = *(const float4*)&W[(size_t)(rowoff + k0 + k) * Dc + colbase + nq * 4];
      *(float4*)&Ws[k][nq * 4] = v;
    }
    __syncthreads();
#pragma unroll
    for (int k = 0; k < 32; ++k) {
      float a[4], w[8];
      *(float4*)&a[0] = *(const float4*)&As[k][m0];
      *(float4*)&w[0] = *(const float4*)&Ws[k][n0];
      *(float4*)&w[4] = *(const float4*)&Ws[k][n0 + 4];
#pragma unroll
      for (int i = 0; i < 4; ++i)
#pragma unroll
        for (int j = 0; j < 8; ++j) acc[i][j] = fmaf(a[i], w[j], acc[i][j]);
    }
    __syncthreads();
  }

  if (seg == 1) {
    float* outp = taskA ? Ta : Tb;
#pragma unroll
    for (int i = 0; i < 4; ++i) {
      int r = row0 + m0 + i;
      if (r >= nrows) continue;
      *(float4*)&outp[(size_t)r * Dc + colbase + n0]     = *(float4*)&acc[i][0];
      *(float4*)&outp[(size_t)r * Dc + colbase + n0 + 4] = *(float4*)&acc[i][4];
    }
  } else {
    float bias[8];
    if (seg == 0) {
#pragma unroll
      for (int j = 0; j < 8; ++j) bias[j] = Fb[colbase + n0 + j];
    }
#pragma unroll
    for (int i = 0; i < 4; ++i) {
      int r = row0 + m0 + i;
      if (r >= nrows) continue;
      unsigned pk[8];
#pragma unroll
      for (int j = 0; j < 8; ++j) {
        float v = acc[i][j];
        if (seg == 0) v = fmaxf(v + bias[j], 0.f);
        pk[j] = pack_hl(v);
      }
      if (seg == 0) {
        unsigned* o = taskA ? Am_hl : FB_hl;
        *(uint4*)&o[(size_t)r * Dc + colbase + n0]     = *(uint4*)&pk[0];
        *(uint4*)&o[(size_t)r * Dc + colbase + n0 + 4] = *(uint4*)&pk[4];
      } else if (!taskA) {
        *(uint4*)&Ub_hl[(size_t)r * Dc + colbase + n0]     = *(uint4*)&pk[0];
        *(uint4*)&Ub_hl[(size_t)r * Dc + colbase + n0 + 4] = *(uint4*)&pk[4];
      } else {
        // transposed: UaT[b][g][s]
        int bI = r >> 7, sI = r & 127;
#pragma unroll
        for (int j = 0; j < 8; ++j)
          UaT[((size_t)(bI * 256 + colbase + n0 + j)) * 128 + sI] = pk[j];
      }
    }
  }
}

// ---------------------------------------------------------------------------
// Fused per-(b,c) MFMA kernel, 1024 threads (16 waves, 4/SIMD).
// LDS word layout:
//   E   [128][68]   e^E matrix, z-contiguous (for P1 A-frags)
//   Et  [64][132]   transposed (for P2 A-frags)
//   SH  [17408]     time-shared: FBg[64][260] -> UaS[128][132] -> UbT[256][68]
//   + stats / reduction scratch
// ---------------------------------------------------------------------------
#define SMEM_WORDS (8704 + 8448 + 17408 + 256 + 64 + 128 + 256 + 512 + 1024 + 64 + 16)
#define SMEM_BYTES (SMEM_WORDS * 4)

__device__ __forceinline__ int ea(int s, int z)  { return s * 68  + (z ^ ((s & 3) << 3)); }
__device__ __forceinline__ int eta(int z, int s) { return z * 132 + (s ^ ((z & 3) << 3)); }
__device__ __forceinline__ int uba(int g, int z) { return g * 68  + (z ^ ((g & 3) << 3)); }

__global__ __launch_bounds__(1024) void fused_kernel(
    const int* __restrict__ cand,
    const unsigned* __restrict__ Am_hl, const unsigned* __restrict__ FB_hl,
    const unsigned* __restrict__ UaT, const unsigned* __restrict__ Ub_hl,
    const float* __restrict__ Ta, const float* __restrict__ Tb,
    const float* __restrict__ Gb,
    float* __restrict__ V1, float* __restrict__ V2)
{
  extern __shared__ char smem[];
  unsigned* E    = (unsigned*)smem;           // 8704
  unsigned* Et   = E + 8704;                  // 8448
  unsigned* SH   = Et + 8448;                 // 17408
  float* gbL  = (float*)(SH + 17408);         // 256
  float* crcp = gbL + 256;                    // 64
  float* rrcp = crcp + 64;                    // 128
  float* rsp  = rrcp + 128;                   // 2*128
  float* csp  = rsp + 256;                    // 8*64
  float* vred = csp + 512;                    // 1024
  int*   cidx = (int*)(vred + 1024);          // 64
  float* gmax = (float*)(cidx + 64);          // 16

  const int bc = blockIdx.x, b = bc >> 6, t = threadIdx.x;
  const int w = t >> 6, l = t & 63, a = l & 15, hq = l >> 4;

  if (t < 64) cidx[t] = cand[(size_t)bc * 64 + t];
  if (t < 256) gbL[t] = Gb[t];
  __syncthreads();

  // ---- stage FBg[z][d] (stride 260), fully coalesced ----
#pragma unroll
  for (int it = 0; it < 4; ++it) {
    int idx = it * 1024 + t;          // 4096 uint4
    int z = idx >> 6, q = idx & 63;
    uint4 v = *(const uint4*)&FB_hl[(size_t)cidx[z] * 256 + q * 4];
    *(uint4*)&SH[z * 260 + q * 4] = v;
  }
  __syncthreads();

  // ---- phase 1: e = Am[b] @ FBg^T. wave: s-tile (w>>1), z-half (w&1) ----
  const int sw = w >> 1, zh = w & 1;
  f4 acc[2];
#pragma unroll
  for (int i = 0; i < 2; ++i)
#pragma unroll
    for (int r = 0; r < 4; ++r) acc[i][r] = 0.f;

  {
    const unsigned* ap = Am_hl + ((size_t)(b * 128 + sw * 16 + a)) * 256;
#pragma unroll
    for (int ch = 0; ch < 8; ++ch) {
      int k0 = ch * 32 + hq * 8;
      HL A = unpack8(*(const uint4*)(ap + k0), *(const uint4*)(ap + k0 + 4));
#pragma unroll
      for (int zt2 = 0; zt2 < 2; ++zt2) {
        const unsigned* bp = &SH[((zh * 2 + zt2) * 16 + a) * 260 + k0];
        HL B = unpack8(*(const uint4*)bp, *(const uint4*)(bp + 4));
        acc[zt2] = mm3(A, B, acc[zt2]);
      }
    }
  }

  // ---- softmax: global max -> E=exp(e-M); row/col sums -> reciprocals ----
  {
    float m = -1e30f;
#pragma unroll
    for (int i = 0; i < 2; ++i)
#pragma unroll
      for (int r = 0; r < 4; ++r) m = fmaxf(m, acc[i][r]);
#pragma unroll
    for (int d = 1; d < 64; d <<= 1) m = fmaxf(m, __shfl_xor(m, d));
    if (l == 0) gmax[w] = m;
    __syncthreads();
    float M = gmax[0];
#pragma unroll
    for (int q = 1; q < 16; ++q) M = fmaxf(M, gmax[q]);

#pragma unroll
    for (int i = 0; i < 2; ++i)
#pragma unroll
      for (int r = 0; r < 4; ++r) acc[i][r] = __expf(acc[i][r] - M);

    // row partial (this wave's 32 z)
#pragma unroll
    for (int r = 0; r < 4; ++r) {
      float rsum = acc[0][r] + acc[1][r];
      rsum += __shfl_xor(rsum, 1); rsum += __shfl_xor(rsum, 2);
      rsum += __shfl_xor(rsum, 4); rsum += __shfl_xor(rsum, 8);
      if (a == 0) rsp[zh * 128 + sw * 16 + hq * 4 + r] = rsum;
    }
    // col partial (this wave's 16 s)
#pragma unroll
    for (int zt2 = 0; zt2 < 2; ++zt2) {
      float c = acc[zt2][0] + acc[zt2][1] + acc[zt2][2] + acc[zt2][3];
      c += __shfl_xor(c, 16); c += __shfl_xor(c, 32);
      if (l < 16) csp[sw * 64 + (zh * 2 + zt2) * 16 + l] = c;
    }
    // pack + store E both orientations
#pragma unroll
    for (int zt2 = 0; zt2 < 2; ++zt2)
#pragma unroll
      for (int r = 0; r < 4; ++r) {
        int s = sw * 16 + hq * 4 + r, z = (zh * 2 + zt2) * 16 + a;
        unsigned pk = pack_hl(acc[zt2][r]);
        E[ea(s, z)] = pk;
        Et[eta(z, s)] = pk;
      }
    __syncthreads();
    if (t < 128) rrcp[t] = 1.f / (rsp[t] + rsp[128 + t]);
    if (t >= 256 && t < 320) {
      int z = t - 256;
      float s = 0.f;
#pragma unroll
      for (int q = 0; q < 8; ++q) s += csp[q * 64 + z];
      crcp[z] = 1.f / s;
    }
    __syncthreads();
  }

  // ---- phase 3a: P2 = Et @ Ua ; V2 = sum_z relu(P2*crcp + Tb + Gb) ----
  // wave: z-tile (w&3), g-group (w>>2) of 2 g-tiles; 2 g-half passes.
  {
    const int zt3 = w & 3, gg3 = w >> 2;
    HL af2[4];
#pragma unroll
    for (int ch = 0; ch < 4; ++ch) {
      int ad = eta(zt3 * 16 + a, ch * 32 + hq * 8);
      af2[ch] = unpack8(*(const uint4*)(Et + ad), *(const uint4*)(Et + ad + 4));
    }
    for (int gh = 0; gh < 2; ++gh) {
      // stage UaS[g'][s] (stride 132), g' in [0,128), coalesced
#pragma unroll
      for (int it = 0; it < 4; ++it) {
        int idx = it * 1024 + t;      // 4096 uint4
        int gp = idx >> 5, q = idx & 31;
        uint4 v = *(const uint4*)&UaT[((size_t)(b * 256 + gh * 128 + gp)) * 128 + q * 4];
        *(uint4*)&SH[gp * 132 + q * 4] = v;
      }
      __syncthreads();

      f4 acc2[2];
#pragma unroll
      for (int i = 0; i < 2; ++i)
#pragma unroll
        for (int r = 0; r < 4; ++r) acc2[i][r] = 0.f;

#pragma unroll
      for (int gt2 = 0; gt2 < 2; ++gt2) {
        int gp = (gg3 * 2 + gt2) * 16 + a;
#pragma unroll
        for (int ch = 0; ch < 4; ++ch) {
          const unsigned* bp = &SH[gp * 132 + ch * 32 + hq * 8];
          HL B = unpack8(*(const uint4*)bp, *(const uint4*)(bp + 4));
          acc2[gt2] = mm3(af2[ch], B, acc2[gt2]);
        }
      }
      // epilogue
#pragma unroll
      for (int gt2 = 0; gt2 < 2; ++gt2) {
        int glo = (gg3 * 2 + gt2) * 16 + a;
        int g = gh * 128 + glo;
        float gb = gbL[g];
        float sv = 0.f;
#pragma unroll
        for (int r = 0; r < 4; ++r) {
          int z = zt3 * 16 + hq * 4 + r;
          float v = fmaf(acc2[gt2][r], crcp[z], Tb[(size_t)cidx[z] * 256 + g] + gb);
          sv += fmaxf(v, 0.f);
        }
        sv += __shfl_xor(sv, 16); sv += __shfl_xor(sv, 32);
        if (l < 16) vred[zt3 * 128 + (gg3 * 2 + gt2) * 16 + l] = sv;
      }
      __syncthreads();
      if (t < 128)
        V2[(size_t)bc * 256 + gh * 128 + t] =
            vred[t] + vred[128 + t] + vred[256 + t] + vred[384 + t];
      // next-half staging (or UbT staging) follows; SH reads finished pre-barrier
    }
  }

  // ---- phase 3b: P1 = E @ UbT ; V1 = sum_s relu(P1*rrcp + Ta + Gb) ----
  {
    // stage UbT[g][z] (stride 68, xor swizzle); loads coalesced, LDS scatter
#pragma unroll
    for (int it = 0; it < 16; ++it) {
      int idx = it * 1024 + t;        // 16384 u32
      int z = idx >> 8, g = idx & 255;
      SH[uba(g, z)] = Ub_hl[(size_t)cidx[z] * 256 + g];
    }
    __syncthreads();

    const int sg = w >> 2, gg = w & 3;   // 2 s-tiles x 4 g-tiles per wave
    HL af1[2][2];
#pragma unroll
    for (int st2 = 0; st2 < 2; ++st2)
#pragma unroll
      for (int ch = 0; ch < 2; ++ch) {
        int ad = ea((sg * 2 + st2) * 16 + a, ch * 32 + hq * 8);
        af1[st2][ch] = unpack8(*(const uint4*)(E + ad), *(const uint4*)(E + ad + 4));
      }
    f4 acc1[2][4];
#pragma unroll
    for (int i = 0; i < 2; ++i)
#pragma unroll
      for (int j = 0; j < 4; ++j)
#pragma unroll
        for (int r = 0; r < 4; ++r) acc1[i][j][r] = 0.f;

#pragma unroll
    for (int gt2 = 0; gt2 < 4; ++gt2) {
      int g = (gg * 4 + gt2) * 16 + a;
#pragma unroll
      for (int ch = 0; ch < 2; ++ch) {
        const unsigned* bp = SH + uba(g, ch * 32 + hq * 8);
        HL B = unpack8(*(const uint4*)bp, *(const uint4*)(bp + 4));
        acc1[0][gt2] = mm3(af1[0][ch], B, acc1[0][gt2]);
        acc1[1][gt2] = mm3(af1[1][ch], B, acc1[1][gt2]);
      }
    }
    // epilogue
#pragma unroll
    for (int gt2 = 0; gt2 < 4; ++gt2) {
      int g = (gg * 4 + gt2) * 16 + a;
      float gb = gbL[g];
      float sv = 0.f;
#pragma unroll
      for (int st2 = 0; st2 < 2; ++st2)
#pragma unroll
        for (int r = 0; r < 4; ++r) {
          int s = (sg * 2 + st2) * 16 + hq * 4 + r;
          float v = fmaf(acc1[st2][gt2][r], rrcp[s],
                         Ta[((size_t)(b * 128 + s)) * 256 + g] + gb);
          sv += fmaxf(v, 0.f);
        }
      sv += __shfl_xor(sv, 16); sv += __shfl_xor(sv, 32);
      if (l < 16) vred[sg * 256 + g] = sv;
    }
    __syncthreads();
    if (t < 256)
      V1[(size_t)bc * 256 + t] =
          vred[t] + vred[256 + t] + vred[512 + t] + vred[768 + t];
  }
}

// ---------------------------------------------------------------------------
// y[bc] = V1[bc]·HW[0:256] + V2[bc]·HW[256:512] + Hb
// ---------------------------------------------------------------------------
__global__ __launch_bounds__(256) void final_kernel(
    const float* __restrict__ V1, const float* __restrict__ V2,
    const float* __restrict__ HW, const float* __restrict__ Hb,
    float* __restrict__ y)
{
  const int t = threadIdx.x;
  const int w = t >> 6, l = t & 63;
  const int bc = blockIdx.x * 4 + w;
  float4 v1 = *(const float4*)&V1[(size_t)bc * Dc + l * 4];
  float4 h1 = *(const float4*)&HW[l * 4];
  float4 v2 = *(const float4*)&V2[(size_t)bc * Dc + l * 4];
  float4 h2 = *(const float4*)&HW[Dc + l * 4];
  float sum = v1.x * h1.x + v1.y * h1.y + v1.z * h1.z + v1.w * h1.w
            + v2.x * h2.x + v2.y * h2.y + v2.z * h2.z + v2.w * h2.w;
#pragma unroll
  for (int off = 32; off > 0; off >>= 1) sum += __shfl_down(sum, off);
  if (l == 0) y[bc] = sum + Hb[0];
}

extern "C" void kernel_launch(void* const* d_in, const int* in_sizes, int n_in,
                              void* d_out, int out_size, void* d_ws, size_t ws_size,
                              hipStream_t stream) {
  (void)in_sizes; (void)n_in; (void)out_size; (void)ws_size;
  const int*   inp  = (const int*)d_in[0];
  const int*   cand = (const int*)d_in[1];
  const float* EmbA = (const float*)d_in[4];
  const float* EmbB = (const float*)d_in[5];
  const float* FW   = (const float*)d_in[6];
  const float* Fb   = (const float*)d_in[7];
  const float* GW   = (const float*)d_in[8];
  const float* Gb   = (const float*)d_in[9];
  const float* HW   = (const float*)d_in[10];
  const float* Hb   = (const float*)d_in[11];
  float* y = (float*)d_out;

  const size_t nA = (size_t)Bc * Sc * Dc;   // 1,048,576
  const size_t nB = (size_t)VOc * Dc;       // 1,280,000
  const size_t nV = (size_t)Bc * Cc * Dc;   //   524,288
  unsigned* Am_hl = (unsigned*)d_ws;
  float*    Ta    = (float*)(Am_hl + nA);
  unsigned* UaT   = (unsigned*)(Ta + nA);
  unsigned* FB_hl = UaT + nA;               // UaT is 32*256*128 = nA
  float*    Tb    = (float*)(FB_hl + nB);
  unsigned* Ub_hl = (unsigned*)(Tb + nB);
  float*    V1    = (float*)(Ub_hl + nB);
  float*    V2    = V1 + nV;                // total ~32.1 MB

  hipFuncSetAttribute((const void*)fused_kernel,
                      hipFuncAttributeMaxDynamicSharedMemorySize, SMEM_BYTES);

  transform_kernel<<<dim3(143, 6), 256, 0, stream>>>(
      EmbA, inp, EmbB, FW, Fb, GW, Am_hl, Ta, UaT, FB_hl, Tb, Ub_hl);
  fused_kernel<<<Bc * Cc, 1024, SMEM_BYTES, stream>>>(
      cand, Am_hl, FB_hl, UaT, Ub_hl, Ta, Tb, Gb, V1, V2);
  final_kernel<<<(Bc * Cc) / 4, 256, 0, stream>>>(V1, V2, HW, Hb, y);
}